// Round 6
// baseline (333.479 us; speedup 1.0000x reference)
//
#include <hip/hip_runtime.h>
#include <cstdint>
#include <cstddef>

#define L_SEQ  2048
#define DMODEL 1024
#define NHEADS 16
#define HDIM   64
#define NQKV   3072

typedef float f32x4 __attribute__((ext_vector_type(4)));
typedef short s16x8 __attribute__((ext_vector_type(8)));

// fp32 -> bf16 round-to-nearest-even (raw bits; finite inputs only)
static __device__ __forceinline__ unsigned short f2bf(float f) {
  unsigned u = __float_as_uint(f);
  return (unsigned short)((u + 0x7fffu + ((u >> 16) & 1u)) >> 16);
}

// async global->LDS, 16B per lane; lds base must be wave-uniform
static __device__ __forceinline__ void gld_lds16(void* lds, const void* g) {
  __builtin_amdgcn_global_load_lds(
      (const __attribute__((address_space(1))) void*)g,
      (__attribute__((address_space(3))) void*)lds, 16, 0, 0);
}

// ---------------------------------------------------------------- convert
__global__ __launch_bounds__(256) void cvt_kernel(
    const float* __restrict__ x, const float* __restrict__ wqkv,
    const float* __restrict__ wout,
    unsigned short* __restrict__ xb, unsigned short* __restrict__ wqkvb,
    unsigned short* __restrict__ woutb) {
  const int NX = L_SEQ * DMODEL / 4;
  const int NW1 = NQKV * DMODEL / 4;
  const int NW2 = DMODEL * DMODEL / 4;
  const int tot = NX + NW1 + NW2;
  for (int i = blockIdx.x * blockDim.x + threadIdx.x; i < tot;
       i += gridDim.x * blockDim.x) {
    const float4* s;
    unsigned short* d;
    int j;
    if (i < NX) { s = (const float4*)x; d = xb; j = i; }
    else if (i < NX + NW1) { s = (const float4*)wqkv; d = wqkvb; j = i - NX; }
    else { s = (const float4*)wout; d = woutb; j = i - NX - NW1; }
    float4 v = s[j];
    ushort4 o;
    o.x = f2bf(v.x); o.y = f2bf(v.y); o.z = f2bf(v.z); o.w = f2bf(v.w);
    *(ushort4*)(d + 4 * (size_t)j) = o;
  }
}

// ------------------------------------------------- shared 128x128 GEMM core
template <int KDIM>
static __device__ __forceinline__ void gemm_bt_core(
    const unsigned short* __restrict__ A, const unsigned short* __restrict__ Bt,
    unsigned short* As, unsigned short* Bs, int bm, int bn, f32x4 acc[4][4]) {
  const int tid = threadIdx.x;
  const int lane = tid & 63;
  const int wave = tid >> 6;
  const int g = lane >> 4;
  const int li = lane & 15;
  const int wm = (wave >> 1) * 64;
  const int wn = (wave & 1) * 64;
  const int arow = tid >> 2;           // 0..63
  const int acolb = (tid & 3) << 4;    // byte offset in 64B row chunk
  const char* gA = (const char*)A + (size_t)(bm * 128 + arow) * (KDIM * 2) + acolb;
  const char* gB = (const char*)Bt + (size_t)(bn * 128 + arow) * (KDIM * 2) + acolb;
  char* lA = (char*)As + wave * 1024;
  char* lB = (char*)Bs + wave * 1024;
  const size_t half = (size_t)64 * KDIM * 2;
  for (int kt = 0; kt < KDIM; kt += 32) {
    __syncthreads();  // prev iter's ds_reads done before overwrite
    gld_lds16(lA, gA + kt * 2);
    gld_lds16(lA + 4096, gA + half + kt * 2);
    gld_lds16(lB, gB + kt * 2);
    gld_lds16(lB + 4096, gB + half + kt * 2);
    __syncthreads();  // staging complete (vmcnt drained by barrier)
    const s16x8* Av = (const s16x8*)As;
    const s16x8* Bv = (const s16x8*)Bs;
    s16x8 af[4], bfv[4];
#pragma unroll
    for (int mt = 0; mt < 4; ++mt) af[mt] = Av[(wm + mt * 16 + li) * 4 + g];
#pragma unroll
    for (int nt = 0; nt < 4; ++nt) bfv[nt] = Bv[(wn + nt * 16 + li) * 4 + g];
#pragma unroll
    for (int mt = 0; mt < 4; ++mt)
#pragma unroll
      for (int nt = 0; nt < 4; ++nt)
        acc[mt][nt] = __builtin_amdgcn_mfma_f32_16x16x32_bf16(
            af[mt], bfv[nt], acc[mt][nt], 0, 0, 0);
  }
}

// ------------------------------------------------------------- QKV GEMM
__global__ __launch_bounds__(256, 2) void gemm_qkv_k(
    const unsigned short* __restrict__ A, const unsigned short* __restrict__ Bt,
    const float* __restrict__ bqkv, unsigned short* __restrict__ Qb,
    unsigned short* __restrict__ Kb, unsigned short* __restrict__ Vt) {
  __shared__ alignas(16) unsigned short As[128 * 32], Bs[128 * 32];
  f32x4 acc[4][4] = {};
  gemm_bt_core<DMODEL>(A, Bt, As, Bs, blockIdx.x, blockIdx.y, acc);
  const int lane = threadIdx.x & 63, wave = threadIdx.x >> 6;
  const int g = lane >> 4, li = lane & 15;
  const int wm = (wave >> 1) * 64, wn = (wave & 1) * 64;
#pragma unroll
  for (int mt = 0; mt < 4; ++mt)
#pragma unroll
    for (int nt = 0; nt < 4; ++nt)
#pragma unroll
      for (int r = 0; r < 4; ++r) {
        int i = blockIdx.x * 128 + wm + mt * 16 + 4 * g + r;
        int n = blockIdx.y * 128 + wn + nt * 16 + li;
        float v = acc[mt][nt][r] + bqkv[n];
        int s = n >> 10;            // 0=q 1=k 2=v (uniform per block)
        int h = (n >> 6) & 15;
        int d = n & 63;
        if (s == 0)      Qb[(((size_t)h * L_SEQ + i) << 6) + d] = f2bf(v * 0.125f);
        else if (s == 1) Kb[(((size_t)h * L_SEQ + i) << 6) + d] = f2bf(v);
        else             Vt[(size_t)(h * 64 + d) * L_SEQ + i] = f2bf(v);
      }
}

// ------------------------------------------------------------- attention
// 2048 blocks (XCD-swizzled: head h confined to XCD h%8), 4 waves split j.
// Bias staged as 1KB-contiguous f32x4 loads -> regs -> swizzled LDS tile
// (double-buffered). VMEM order per tile: K (L2), V (L2), bias[t+1] (HBM)
// so counted in-order vmcnt waits never drain the bias prefetch.
__global__ __launch_bounds__(256, 3) void attn_k(
    const unsigned short* __restrict__ Qb, const unsigned short* __restrict__ Kb,
    const unsigned short* __restrict__ Vt, const float* __restrict__ bias,
    const float* __restrict__ gate, unsigned short* __restrict__ AO) {
  __shared__ alignas(16) float blds[2][16 * 256];  // 2 x 16KB bias tiles
  __shared__ alignas(16) char plds[4 * 2048];      // P transpose, 2KB/wave
  const int bid = blockIdx.x;
  const int slot = bid >> 3;                 // 0..255
  const int h = (bid & 7) + 8 * (slot >> 7); // head -> XCD bid%8
  const int i0 = (slot & 127) * 16;
  const int tid = threadIdx.x, lane = tid & 63, wave = tid >> 6;
  const int g = lane >> 4, li = lane & 15;
  char* myP = plds + wave * 2048;
  const s16x8* Qv = (const s16x8*)(Qb + (((size_t)h * L_SEQ + i0) << 6));
  const s16x8 qf0 = Qv[li * 8 + g];
  const s16x8 qf1 = Qv[li * 8 + 4 + g];
  const float gh = gate[h];
  const float* bh = bias + (size_t)h * L_SEQ * L_SEQ + (size_t)i0 * L_SEQ;
  const s16x8* Kall = (const s16x8*)(Kb + (((size_t)h * L_SEQ) << 6));
  f32x4 accO[4] = {};
  f32x4 lpart = {0.f, 0.f, 0.f, 0.f};
  const int swzg = (g << 2) | ((g & 1) << 4);  // read-side bank swizzle
  const int srow = 4 * wave;                   // this wave stages rows srow..+3

  // prologue: bias tile 0 -> regs -> LDS buf0 (col c stored at dword c^swz(row))
  {
    f32x4 rb[4];
#pragma unroll
    for (int q = 0; q < 4; ++q)
      rb[q] = *(const f32x4*)(bh + (size_t)(srow + q) * L_SEQ + 4 * lane);
#pragma unroll
    for (int q = 0; q < 4; ++q) {
      const int rr = srow + q, G = (rr >> 2) & 3;
      const int sw = (G << 2) | ((G & 1) << 4);
      *(f32x4*)&blds[0][rr * 256 + ((4 * lane) ^ sw)] = rb[q];
    }
    asm volatile("s_waitcnt lgkmcnt(0)" ::: "memory");
  }

#pragma unroll
  for (int t = 0; t < 8; ++t) {
    const int j0 = t * 256 + wave * 64;
    // --- VMEM issue order matters (in-order vmcnt): K, V, then bias[t+1]
    s16x8 k0[4], k1[4];
#pragma unroll
    for (int nt = 0; nt < 4; ++nt) {
      k0[nt] = Kall[(j0 + nt * 16 + li) * 8 + g];
      k1[nt] = Kall[(j0 + nt * 16 + li) * 8 + 4 + g];
    }
    s16x8 v0[4], v1[4];
#pragma unroll
    for (int dt = 0; dt < 4; ++dt) {
      const unsigned short* vb = Vt + (size_t)(h * 64 + dt * 16 + li) * L_SEQ + j0;
      v0[dt] = *(const s16x8*)(vb + 8 * g);
      v1[dt] = *(const s16x8*)(vb + 32 + 8 * g);
    }
    f32x4 rb[4];
    if (t < 7) {
#pragma unroll
      for (int q = 0; q < 4; ++q)
        rb[q] = *(const f32x4*)(bh + (size_t)(srow + q) * L_SEQ +
                                (t + 1) * 256 + 4 * lane);
    }
    __builtin_amdgcn_s_barrier();  // raw: bias[t] visible; no vmcnt drain
    // QK^T
    f32x4 s[4];
#pragma unroll
    for (int nt = 0; nt < 4; ++nt) {
      f32x4 z = {0.f, 0.f, 0.f, 0.f};
      z = __builtin_amdgcn_mfma_f32_16x16x32_bf16(qf0, k0[nt], z, 0, 0, 0);
      z = __builtin_amdgcn_mfma_f32_16x16x32_bf16(qf1, k1[nt], z, 0, 0, 0);
      s[nt] = z;
    }
    // p = exp(s + gh*bias_lds); per-lane denom; P -> wave-local LDS (swizzled)
    const float* bl = blds[t & 1];
#pragma unroll
    for (int nt = 0; nt < 4; ++nt)
#pragma unroll
      for (int r = 0; r < 4; ++r) {
        const int row = 4 * g + r;
        const int cc = wave * 64 + nt * 16 + li;
        float p = __expf(fmaf(gh, bl[row * 256 + (cc ^ swzg)], s[nt][r]));
        lpart[r] += p;
        unsigned b = (unsigned)(row * 128 + (nt * 16 + li) * 2) ^
                     (unsigned)((row & 7) << 4);
        *(unsigned short*)(myP + b) = f2bf(p);
      }
    asm volatile("s_waitcnt lgkmcnt(0)" ::: "memory");
    const unsigned b0 = ((unsigned)(li * 128 + 16 * g)) ^ (unsigned)((li & 7) << 4);
    const unsigned b1 = ((unsigned)(li * 128 + 64 + 16 * g)) ^ (unsigned)((li & 7) << 4);
    const s16x8 pa0 = *(const s16x8*)(myP + b0);
    const s16x8 pa1 = *(const s16x8*)(myP + b1);
#pragma unroll
    for (int dt = 0; dt < 4; ++dt) {
      accO[dt] = __builtin_amdgcn_mfma_f32_16x16x32_bf16(pa0, v0[dt], accO[dt], 0, 0, 0);
      accO[dt] = __builtin_amdgcn_mfma_f32_16x16x32_bf16(pa1, v1[dt], accO[dt], 0, 0, 0);
    }
    // stage bias[t+1] into the other buffer (consumes rb -> vmcnt wait here)
    if (t < 7) {
#pragma unroll
      for (int q = 0; q < 4; ++q) {
        const int rr = srow + q, G = (rr >> 2) & 3;
        const int sw = (G << 2) | ((G & 1) << 4);
        *(f32x4*)&blds[(t + 1) & 1][rr * 256 + ((4 * lane) ^ sw)] = rb[q];
      }
    }
    asm volatile("s_waitcnt lgkmcnt(0)" ::: "memory");  // writer drain for barrier
  }
  // denom across the 16 lanes of each row group
  float lrow[4];
#pragma unroll
  for (int r = 0; r < 4; ++r) {
    float tl = lpart[r];
    tl += __shfl_xor(tl, 1);
    tl += __shfl_xor(tl, 2);
    tl += __shfl_xor(tl, 4);
    tl += __shfl_xor(tl, 8);
    lrow[r] = tl;
  }
  __syncthreads();  // full drain before LDS reuse for combine
  float* accL = &blds[0][0];   // [4][16][64] = 16KB
  float* lL = &blds[1][0];     // [4][16]
#pragma unroll
  for (int dt = 0; dt < 4; ++dt)
#pragma unroll
    for (int r = 0; r < 4; ++r)
      accL[(wave * 16 + 4 * g + r) * 64 + dt * 16 + li] = accO[dt][r];
  if (li == 0) {
#pragma unroll
    for (int r = 0; r < 4; ++r) lL[wave * 16 + 4 * g + r] = lrow[r];
  }
  __syncthreads();
  {
    const int row = tid >> 4;         // 0..15
    const int c0 = (tid & 15) * 4;    // col base
    f32x4 sum = {0.f, 0.f, 0.f, 0.f};
    float lsum = 0.f;
#pragma unroll
    for (int w = 0; w < 4; ++w) {
      const f32x4 a = *(const f32x4*)&accL[(w * 16 + row) * 64 + c0];
      sum += a;
      lsum += lL[w * 16 + row];
    }
    const float inv = 1.0f / lsum;
    ushort4 o;
    o.x = f2bf(sum[0] * inv);
    o.y = f2bf(sum[1] * inv);
    o.z = f2bf(sum[2] * inv);
    o.w = f2bf(sum[3] * inv);
    *(ushort4*)(AO + (size_t)(i0 + row) * DMODEL + h * 64 + c0) = o;
  }
}

// ------------------------------------------------------------- out proj
__global__ __launch_bounds__(256, 2) void gemm_out_k(
    const unsigned short* __restrict__ A, const unsigned short* __restrict__ Bt,
    const float* __restrict__ bout, float* __restrict__ out) {
  __shared__ alignas(16) unsigned short As[128 * 32], Bs[128 * 32];
  f32x4 acc[4][4] = {};
  gemm_bt_core<DMODEL>(A, Bt, As, Bs, blockIdx.x, blockIdx.y, acc);
  const int lane = threadIdx.x & 63, wave = threadIdx.x >> 6;
  const int g = lane >> 4, li = lane & 15;
  const int wm = (wave >> 1) * 64, wn = (wave & 1) * 64;
#pragma unroll
  for (int mt = 0; mt < 4; ++mt)
#pragma unroll
    for (int nt = 0; nt < 4; ++nt)
#pragma unroll
      for (int r = 0; r < 4; ++r) {
        int i = blockIdx.x * 128 + wm + mt * 16 + 4 * g + r;
        int n = blockIdx.y * 128 + wn + nt * 16 + li;
        out[(size_t)i * DMODEL + n] = acc[mt][nt][r] + bout[n];
      }
}

// ---------------------------------------------------------------- launch
extern "C" void kernel_launch(void* const* d_in, const int* in_sizes, int n_in,
                              void* d_out, int out_size, void* d_ws,
                              size_t ws_size, hipStream_t stream) {
  const float* x = (const float*)d_in[0];
  const float* pb = (const float*)d_in[1];
  const float* gate = (const float*)d_in[2];
  const float* wqkv = (const float*)d_in[3];
  const float* bqkv = (const float*)d_in[4];
  const float* wout = (const float*)d_in[5];
  const float* bout = (const float*)d_in[6];

  unsigned short* ws = (unsigned short*)d_ws;
  unsigned short* xb = ws;
  unsigned short* wqkvb = xb + (size_t)L_SEQ * DMODEL;
  unsigned short* woutb = wqkvb + (size_t)NQKV * DMODEL;
  unsigned short* Qb = woutb + (size_t)DMODEL * DMODEL;
  unsigned short* Kb = Qb + (size_t)NHEADS * L_SEQ * HDIM;
  unsigned short* Vt = Kb + (size_t)NHEADS * L_SEQ * HDIM;
  unsigned short* AO = Vt + (size_t)NHEADS * L_SEQ * HDIM;

  cvt_kernel<<<1024, 256, 0, stream>>>(x, wqkv, wout, xb, wqkvb, woutb);
  gemm_qkv_k<<<dim3(16, 24), 256, 0, stream>>>(xb, wqkvb, bqkv, Qb, Kb, Vt);
  attn_k<<<2048, 256, 0, stream>>>(Qb, Kb, Vt, pb, gate, AO);
  gemm_out_k<<<dim3(16, 8), 256, 0, stream>>>(AO, woutb, bout, (float*)d_out);
}

// Round 7
// 236.290 us; speedup vs baseline: 1.4113x; 1.4113x over previous
//
#include <hip/hip_runtime.h>
#include <cstdint>
#include <cstddef>

#define L_SEQ  2048
#define DMODEL 1024
#define NHEADS 16
#define HDIM   64
#define NQKV   3072
#define JC     512   // bias cols per score block

typedef float f32x4 __attribute__((ext_vector_type(4)));
typedef short s16x8 __attribute__((ext_vector_type(8)));

// fp32 -> bf16 round-to-nearest-even (raw bits; finite inputs only)
static __device__ __forceinline__ unsigned short f2bf(float f) {
  unsigned u = __float_as_uint(f);
  return (unsigned short)((u + 0x7fffu + ((u >> 16) & 1u)) >> 16);
}

static __device__ __forceinline__ float bf2f(unsigned short u) {
  return __uint_as_float(((unsigned)u) << 16);
}

// async global->LDS, 16B per lane; lds base wave-uniform, global per-lane
static __device__ __forceinline__ void gld_lds16(void* lds, const void* g) {
  __builtin_amdgcn_global_load_lds(
      (const __attribute__((address_space(1))) void*)g,
      (__attribute__((address_space(3))) void*)lds, 16, 0, 0);
}

// ---------------------------------------------------------------- convert
__global__ __launch_bounds__(256) void cvt_kernel(
    const float* __restrict__ x, const float* __restrict__ wqkv,
    const float* __restrict__ wout,
    unsigned short* __restrict__ xb, unsigned short* __restrict__ wqkvb,
    unsigned short* __restrict__ woutb) {
  const int NX = L_SEQ * DMODEL / 4;
  const int NW1 = NQKV * DMODEL / 4;
  const int NW2 = DMODEL * DMODEL / 4;
  const int tot = NX + NW1 + NW2;
  for (int i = blockIdx.x * blockDim.x + threadIdx.x; i < tot;
       i += gridDim.x * blockDim.x) {
    const float4* s;
    unsigned short* d;
    int j;
    if (i < NX) { s = (const float4*)x; d = xb; j = i; }
    else if (i < NX + NW1) { s = (const float4*)wqkv; d = wqkvb; j = i - NX; }
    else { s = (const float4*)wout; d = woutb; j = i - NX - NW1; }
    float4 v = s[j];
    ushort4 o;
    o.x = f2bf(v.x); o.y = f2bf(v.y); o.z = f2bf(v.z); o.w = f2bf(v.w);
    *(ushort4*)(d + 4 * (size_t)j) = o;
  }
}

// ------------------------------------------------- shared 128x128 GEMM core
template <int KDIM>
static __device__ __forceinline__ void gemm_bt_core(
    const unsigned short* __restrict__ A, const unsigned short* __restrict__ Bt,
    unsigned short* As, unsigned short* Bs, int bm, int bn, f32x4 acc[4][4]) {
  const int tid = threadIdx.x;
  const int lane = tid & 63;
  const int wave = tid >> 6;
  const int g = lane >> 4;
  const int li = lane & 15;
  const int wm = (wave >> 1) * 64;
  const int wn = (wave & 1) * 64;
  const int arow = tid >> 2;           // 0..63
  const int acolb = (tid & 3) << 4;    // byte offset in 64B row chunk
  const char* gA = (const char*)A + (size_t)(bm * 128 + arow) * (KDIM * 2) + acolb;
  const char* gB = (const char*)Bt + (size_t)(bn * 128 + arow) * (KDIM * 2) + acolb;
  char* lA = (char*)As + wave * 1024;
  char* lB = (char*)Bs + wave * 1024;
  const size_t half = (size_t)64 * KDIM * 2;
  for (int kt = 0; kt < KDIM; kt += 32) {
    __syncthreads();  // prev iter's ds_reads done before overwrite
    gld_lds16(lA, gA + kt * 2);
    gld_lds16(lA + 4096, gA + half + kt * 2);
    gld_lds16(lB, gB + kt * 2);
    gld_lds16(lB + 4096, gB + half + kt * 2);
    __syncthreads();  // staging complete (vmcnt drained by barrier)
    const s16x8* Av = (const s16x8*)As;
    const s16x8* Bv = (const s16x8*)Bs;
    s16x8 af[4], bfv[4];
#pragma unroll
    for (int mt = 0; mt < 4; ++mt) af[mt] = Av[(wm + mt * 16 + li) * 4 + g];
#pragma unroll
    for (int nt = 0; nt < 4; ++nt) bfv[nt] = Bv[(wn + nt * 16 + li) * 4 + g];
#pragma unroll
    for (int mt = 0; mt < 4; ++mt)
#pragma unroll
      for (int nt = 0; nt < 4; ++nt)
        acc[mt][nt] = __builtin_amdgcn_mfma_f32_16x16x32_bf16(
            af[mt], bfv[nt], acc[mt][nt], 0, 0, 0);
  }
}

// ------------------------------------------------------------- QKV GEMM
__global__ __launch_bounds__(256, 2) void gemm_qkv_k(
    const unsigned short* __restrict__ A, const unsigned short* __restrict__ Bt,
    const float* __restrict__ bqkv, unsigned short* __restrict__ Qb,
    unsigned short* __restrict__ Kb, unsigned short* __restrict__ Vt) {
  __shared__ alignas(16) unsigned short As[128 * 32], Bs[128 * 32];
  f32x4 acc[4][4] = {};
  gemm_bt_core<DMODEL>(A, Bt, As, Bs, blockIdx.x, blockIdx.y, acc);
  const int lane = threadIdx.x & 63, wave = threadIdx.x >> 6;
  const int g = lane >> 4, li = lane & 15;
  const int wm = (wave >> 1) * 64, wn = (wave & 1) * 64;
#pragma unroll
  for (int mt = 0; mt < 4; ++mt)
#pragma unroll
    for (int nt = 0; nt < 4; ++nt)
#pragma unroll
      for (int r = 0; r < 4; ++r) {
        int i = blockIdx.x * 128 + wm + mt * 16 + 4 * g + r;
        int n = blockIdx.y * 128 + wn + nt * 16 + li;
        float v = acc[mt][nt][r] + bqkv[n];
        int s = n >> 10;            // 0=q 1=k 2=v (uniform per block)
        int h = (n >> 6) & 15;
        int d = n & 63;
        if (s == 0)      Qb[(((size_t)h * L_SEQ + i) << 6) + d] = f2bf(v * 0.125f);
        else if (s == 1) Kb[(((size_t)h * L_SEQ + i) << 6) + d] = f2bf(v);
        else             Vt[(size_t)(h * 64 + d) * L_SEQ + i] = f2bf(v);
      }
}

// ------------------------------------------- attention A: scores -> E frags
// grid (128 i-tiles, 4 j-chunks of 512, 16 heads). Phase A: bias -> LDS via
// pure DMA (8x 1KB per wave, no registers). Phase B: QK MFMA + exp + wave-
// local transpose; E stored in fragment order (1KB coalesced wave-stores).
__global__ __launch_bounds__(256) void attn_score_k(
    const unsigned short* __restrict__ Qb, const unsigned short* __restrict__ Kb,
    const float* __restrict__ bias, const float* __restrict__ gate,
    unsigned short* __restrict__ E) {
  __shared__ alignas(16) float blds[16][JC];   // 32 KB
  __shared__ alignas(16) char plds[4 * 2048];  // 8 KB P transpose
  const int h = blockIdx.z, it = blockIdx.x, jc = blockIdx.y;
  const int i0 = it * 16;
  const int tid = threadIdx.x, lane = tid & 63, wave = tid >> 6;
  const int g = lane >> 4, li = lane & 15;
  char* myP = plds + wave * 2048;
  // phase A: wave stages bias rows 4w..4w+3 (1KB contiguous per DMA op)
  const float* bh = bias + (size_t)h * L_SEQ * L_SEQ + (size_t)i0 * L_SEQ + jc * JC;
#pragma unroll
  for (int q = 0; q < 4; ++q) {
    const int r = 4 * wave + q;
    const char* gsrc = (const char*)(bh + (size_t)r * L_SEQ) + lane * 16;
    gld_lds16(&blds[r][0], gsrc);
    gld_lds16(&blds[r][256], gsrc + 1024);
  }
  const s16x8* Qv = (const s16x8*)(Qb + (((size_t)h * L_SEQ + i0) << 6));
  const s16x8 qf0 = Qv[li * 8 + g];
  const s16x8 qf1 = Qv[li * 8 + 4 + g];
  const float gh = gate[h];
  const s16x8* Kall = (const s16x8*)(Kb + (((size_t)h * L_SEQ) << 6));
  __syncthreads();  // full drain: bias tile visible
#pragma unroll
  for (int st = 0; st < 2; ++st) {
    const int c0 = wave * 128 + st * 64;   // col base within JC
    const int jg = jc * JC + c0;           // global col base
    s16x8 k0[4], k1[4];
#pragma unroll
    for (int nt = 0; nt < 4; ++nt) {
      k0[nt] = Kall[(jg + nt * 16 + li) * 8 + g];
      k1[nt] = Kall[(jg + nt * 16 + li) * 8 + 4 + g];
    }
    f32x4 s[4];
#pragma unroll
    for (int nt = 0; nt < 4; ++nt) {
      f32x4 z = {0.f, 0.f, 0.f, 0.f};
      z = __builtin_amdgcn_mfma_f32_16x16x32_bf16(qf0, k0[nt], z, 0, 0, 0);
      z = __builtin_amdgcn_mfma_f32_16x16x32_bf16(qf1, k1[nt], z, 0, 0, 0);
      s[nt] = z;
    }
#pragma unroll
    for (int nt = 0; nt < 4; ++nt)
#pragma unroll
      for (int r = 0; r < 4; ++r) {
        const int row = 4 * g + r;
        float p = __expf(fmaf(gh, blds[row][c0 + nt * 16 + li], s[nt][r]));
        unsigned b = (unsigned)(row * 128 + (nt * 16 + li) * 2) ^
                     (unsigned)((row & 7) << 4);
        *(unsigned short*)(myP + b) = f2bf(p);
      }
    asm volatile("s_waitcnt lgkmcnt(0)" ::: "memory");
    const unsigned b0 = ((unsigned)(li * 128 + 16 * g)) ^ (unsigned)((li & 7) << 4);
    const unsigned b1 = ((unsigned)(li * 128 + 64 + 16 * g)) ^ (unsigned)((li & 7) << 4);
    const s16x8 pa0 = *(const s16x8*)(myP + b0);
    const s16x8 pa1 = *(const s16x8*)(myP + b1);
    // E in fragment order: unit = ((h*128+it)*32+js)*128 + part*64 + lane
    const int js = jc * 8 + wave * 2 + st;
    unsigned short* Eo =
        E + ((((size_t)h * 128 + it) * 32 + js) * 128 + lane) * 8;
    *(s16x8*)Eo = pa0;
    *(s16x8*)(Eo + 512) = pa1;   // +64 units
  }
}

// ------------------------------------------- attention B: PV + normalize
// grid (128 i-tiles, 16 heads); 4 waves split js; E-frag reads are 1KB
// coalesced wave-loads (L3-resident). Denominator from same bf16 E values.
__global__ __launch_bounds__(256) void attn_pv_k(
    const unsigned short* __restrict__ E, const unsigned short* __restrict__ Vt,
    unsigned short* __restrict__ AO) {
  __shared__ alignas(16) char lds[16 * 1024 + 256];
  const int h = blockIdx.y, it = blockIdx.x;
  const int i0 = it * 16;
  const int tid = threadIdx.x, lane = tid & 63, wave = tid >> 6;
  const int g = lane >> 4, li = lane & 15;
  const size_t ebase = ((size_t)h * 128 + it) * 32 * 128;
  f32x4 accO[4] = {};
  float lsum = 0.f;
#pragma unroll
  for (int t = 0; t < 8; ++t) {
    const int js = t * 4 + wave;
    const int j0 = js * 64;
    const unsigned short* Eo = E + (ebase + (size_t)js * 128 + lane) * 8;
    const s16x8 pa0 = *(const s16x8*)Eo;
    const s16x8 pa1 = *(const s16x8*)(Eo + 512);
#pragma unroll
    for (int e = 0; e < 8; ++e)
      lsum += bf2f((unsigned short)pa0[e]) + bf2f((unsigned short)pa1[e]);
#pragma unroll
    for (int dt = 0; dt < 4; ++dt) {
      const unsigned short* vb = Vt + (size_t)(h * 64 + dt * 16 + li) * L_SEQ + j0;
      const s16x8 v0 = *(const s16x8*)(vb + 8 * g);
      const s16x8 v1 = *(const s16x8*)(vb + 32 + 8 * g);
      accO[dt] = __builtin_amdgcn_mfma_f32_16x16x32_bf16(pa0, v0, accO[dt], 0, 0, 0);
      accO[dt] = __builtin_amdgcn_mfma_f32_16x16x32_bf16(pa1, v1, accO[dt], 0, 0, 0);
    }
  }
  // lane holds partial denom for row i0+li; combine across g
  lsum += __shfl_xor(lsum, 16);
  lsum += __shfl_xor(lsum, 32);
  float* accL = (float*)lds;                 // [4][16][64]
  float* lL = (float*)(lds + 16 * 1024);     // [4][16]
#pragma unroll
  for (int dt = 0; dt < 4; ++dt)
#pragma unroll
    for (int r = 0; r < 4; ++r)
      accL[(wave * 16 + 4 * g + r) * 64 + dt * 16 + li] = accO[dt][r];
  if (lane < 16) lL[wave * 16 + lane] = lsum;
  __syncthreads();
  {
    const int row = tid >> 4;         // 0..15
    const int c0 = (tid & 15) * 4;    // col base
    f32x4 sum = {0.f, 0.f, 0.f, 0.f};
    float ls = 0.f;
#pragma unroll
    for (int w = 0; w < 4; ++w) {
      const f32x4 a = *(const f32x4*)&accL[(w * 16 + row) * 64 + c0];
      sum += a;
      ls += lL[w * 16 + row];
    }
    const float inv = 1.0f / ls;
    ushort4 o;
    o.x = f2bf(sum[0] * inv);
    o.y = f2bf(sum[1] * inv);
    o.z = f2bf(sum[2] * inv);
    o.w = f2bf(sum[3] * inv);
    *(ushort4*)(AO + (size_t)(i0 + row) * DMODEL + h * 64 + c0) = o;
  }
}

// ------------------------------------------------------------- out proj
__global__ __launch_bounds__(256, 2) void gemm_out_k(
    const unsigned short* __restrict__ A, const unsigned short* __restrict__ Bt,
    const float* __restrict__ bout, float* __restrict__ out) {
  __shared__ alignas(16) unsigned short As[128 * 32], Bs[128 * 32];
  f32x4 acc[4][4] = {};
  gemm_bt_core<DMODEL>(A, Bt, As, Bs, blockIdx.x, blockIdx.y, acc);
  const int lane = threadIdx.x & 63, wave = threadIdx.x >> 6;
  const int g = lane >> 4, li = lane & 15;
  const int wm = (wave >> 1) * 64, wn = (wave & 1) * 64;
#pragma unroll
  for (int mt = 0; mt < 4; ++mt)
#pragma unroll
    for (int nt = 0; nt < 4; ++nt)
#pragma unroll
      for (int r = 0; r < 4; ++r) {
        int i = blockIdx.x * 128 + wm + mt * 16 + 4 * g + r;
        int n = blockIdx.y * 128 + wn + nt * 16 + li;
        out[(size_t)i * DMODEL + n] = acc[mt][nt][r] + bout[n];
      }
}

// ---------------------------------------------------------------- launch
extern "C" void kernel_launch(void* const* d_in, const int* in_sizes, int n_in,
                              void* d_out, int out_size, void* d_ws,
                              size_t ws_size, hipStream_t stream) {
  const float* x = (const float*)d_in[0];
  const float* pb = (const float*)d_in[1];
  const float* gate = (const float*)d_in[2];
  const float* wqkv = (const float*)d_in[3];
  const float* bqkv = (const float*)d_in[4];
  const float* wout = (const float*)d_in[5];
  const float* bout = (const float*)d_in[6];

  unsigned short* ws = (unsigned short*)d_ws;
  unsigned short* xb = ws;
  unsigned short* wqkvb = xb + (size_t)L_SEQ * DMODEL;
  unsigned short* woutb = wqkvb + (size_t)NQKV * DMODEL;
  unsigned short* Qb = woutb + (size_t)DMODEL * DMODEL;
  unsigned short* Kb = Qb + (size_t)NHEADS * L_SEQ * HDIM;
  unsigned short* Vt = Kb + (size_t)NHEADS * L_SEQ * HDIM;
  unsigned short* AO = Vt + (size_t)NHEADS * L_SEQ * HDIM;
  unsigned short* E  = AO + (size_t)L_SEQ * DMODEL;   // 128MB frag-order bf16

  cvt_kernel<<<1024, 256, 0, stream>>>(x, wqkv, wout, xb, wqkvb, woutb);
  gemm_qkv_k<<<dim3(16, 24), 256, 0, stream>>>(xb, wqkvb, bqkv, Qb, Kb, Vt);
  attn_score_k<<<dim3(128, 4, 16), 256, 0, stream>>>(Qb, Kb, pb, gate, E);
  attn_pv_k<<<dim3(128, 16), 256, 0, stream>>>(E, Vt, AO);
  gemm_out_k<<<dim3(16, 8), 256, 0, stream>>>(AO, woutb, bout, (float*)d_out);
}

// Round 8
// 210.764 us; speedup vs baseline: 1.5822x; 1.1211x over previous
//
#include <hip/hip_runtime.h>
#include <cstdint>
#include <cstddef>

#define L_SEQ  2048
#define DMODEL 1024
#define NHEADS 16
#define HDIM   64
#define NQKV   3072
#define JC     512   // bias cols per fused block

typedef float f32x4 __attribute__((ext_vector_type(4)));
typedef short s16x8 __attribute__((ext_vector_type(8)));

// fp32 -> bf16 round-to-nearest-even (raw bits; finite inputs only)
static __device__ __forceinline__ unsigned short f2bf(float f) {
  unsigned u = __float_as_uint(f);
  return (unsigned short)((u + 0x7fffu + ((u >> 16) & 1u)) >> 16);
}

static __device__ __forceinline__ float bf2f(unsigned short u) {
  return __uint_as_float(((unsigned)u) << 16);
}

// async global->LDS, 16B per lane; lds base wave-uniform, global per-lane
static __device__ __forceinline__ void gld_lds16(void* lds, const void* g) {
  __builtin_amdgcn_global_load_lds(
      (const __attribute__((address_space(1))) void*)g,
      (__attribute__((address_space(3))) void*)lds, 16, 0, 0);
}

// ---------------------------------------------------------------- convert
__global__ __launch_bounds__(256) void cvt_kernel(
    const float* __restrict__ x, const float* __restrict__ wqkv,
    const float* __restrict__ wout,
    unsigned short* __restrict__ xb, unsigned short* __restrict__ wqkvb,
    unsigned short* __restrict__ woutb) {
  const int NX = L_SEQ * DMODEL / 4;
  const int NW1 = NQKV * DMODEL / 4;
  const int NW2 = DMODEL * DMODEL / 4;
  const int tot = NX + NW1 + NW2;
  for (int i = blockIdx.x * blockDim.x + threadIdx.x; i < tot;
       i += gridDim.x * blockDim.x) {
    const float4* s;
    unsigned short* d;
    int j;
    if (i < NX) { s = (const float4*)x; d = xb; j = i; }
    else if (i < NX + NW1) { s = (const float4*)wqkv; d = wqkvb; j = i - NX; }
    else { s = (const float4*)wout; d = woutb; j = i - NX - NW1; }
    float4 v = s[j];
    ushort4 o;
    o.x = f2bf(v.x); o.y = f2bf(v.y); o.z = f2bf(v.z); o.w = f2bf(v.w);
    *(ushort4*)(d + 4 * (size_t)j) = o;
  }
}

// ------------------------------------------------- shared 128x128 GEMM core
template <int KDIM>
static __device__ __forceinline__ void gemm_bt_core(
    const unsigned short* __restrict__ A, const unsigned short* __restrict__ Bt,
    unsigned short* As, unsigned short* Bs, int bm, int bn, f32x4 acc[4][4]) {
  const int tid = threadIdx.x;
  const int lane = tid & 63;
  const int wave = tid >> 6;
  const int g = lane >> 4;
  const int li = lane & 15;
  const int wm = (wave >> 1) * 64;
  const int wn = (wave & 1) * 64;
  const int arow = tid >> 2;           // 0..63
  const int acolb = (tid & 3) << 4;    // byte offset in 64B row chunk
  const char* gA = (const char*)A + (size_t)(bm * 128 + arow) * (KDIM * 2) + acolb;
  const char* gB = (const char*)Bt + (size_t)(bn * 128 + arow) * (KDIM * 2) + acolb;
  char* lA = (char*)As + wave * 1024;
  char* lB = (char*)Bs + wave * 1024;
  const size_t half = (size_t)64 * KDIM * 2;
  for (int kt = 0; kt < KDIM; kt += 32) {
    __syncthreads();  // prev iter's ds_reads done before overwrite
    gld_lds16(lA, gA + kt * 2);
    gld_lds16(lA + 4096, gA + half + kt * 2);
    gld_lds16(lB, gB + kt * 2);
    gld_lds16(lB + 4096, gB + half + kt * 2);
    __syncthreads();  // staging complete (vmcnt drained by barrier)
    const s16x8* Av = (const s16x8*)As;
    const s16x8* Bv = (const s16x8*)Bs;
    s16x8 af[4], bfv[4];
#pragma unroll
    for (int mt = 0; mt < 4; ++mt) af[mt] = Av[(wm + mt * 16 + li) * 4 + g];
#pragma unroll
    for (int nt = 0; nt < 4; ++nt) bfv[nt] = Bv[(wn + nt * 16 + li) * 4 + g];
#pragma unroll
    for (int mt = 0; mt < 4; ++mt)
#pragma unroll
      for (int nt = 0; nt < 4; ++nt)
        acc[mt][nt] = __builtin_amdgcn_mfma_f32_16x16x32_bf16(
            af[mt], bfv[nt], acc[mt][nt], 0, 0, 0);
  }
}

// ------------------------------------------------------------- QKV GEMM
__global__ __launch_bounds__(256, 2) void gemm_qkv_k(
    const unsigned short* __restrict__ A, const unsigned short* __restrict__ Bt,
    const float* __restrict__ bqkv, unsigned short* __restrict__ Qb,
    unsigned short* __restrict__ Kb, unsigned short* __restrict__ Vt) {
  __shared__ alignas(16) unsigned short As[128 * 32], Bs[128 * 32];
  f32x4 acc[4][4] = {};
  gemm_bt_core<DMODEL>(A, Bt, As, Bs, blockIdx.x, blockIdx.y, acc);
  const int lane = threadIdx.x & 63, wave = threadIdx.x >> 6;
  const int g = lane >> 4, li = lane & 15;
  const int wm = (wave >> 1) * 64, wn = (wave & 1) * 64;
#pragma unroll
  for (int mt = 0; mt < 4; ++mt)
#pragma unroll
    for (int nt = 0; nt < 4; ++nt)
#pragma unroll
      for (int r = 0; r < 4; ++r) {
        int i = blockIdx.x * 128 + wm + mt * 16 + 4 * g + r;
        int n = blockIdx.y * 128 + wn + nt * 16 + li;
        float v = acc[mt][nt][r] + bqkv[n];
        int s = n >> 10;            // 0=q 1=k 2=v (uniform per block)
        int h = (n >> 6) & 15;
        int d = n & 63;
        if (s == 0)      Qb[(((size_t)h * L_SEQ + i) << 6) + d] = f2bf(v * 0.125f);
        else if (s == 1) Kb[(((size_t)h * L_SEQ + i) << 6) + d] = f2bf(v);
        else             Vt[(size_t)(h * 64 + d) * L_SEQ + i] = f2bf(v);
      }
}

// --------------------------------- fused attention: scores+PV per j-chunk
// grid (128 i-tiles, 4 j-chunks of 512, 16 heads). No-max softmax makes
// j-chunk partials additive: each block writes unnormalized partial O (f32)
// + partial denominators; combiner sums 4 chunks and normalizes.
// Pattern: bias -> LDS via pure DMA, one __syncthreads, then compute
// (K/V register loads are L2-resident; no cross-barrier VMEM registers).
__global__ __launch_bounds__(256) void attn_fused_k(
    const unsigned short* __restrict__ Qb, const unsigned short* __restrict__ Kb,
    const unsigned short* __restrict__ Vt, const float* __restrict__ bias,
    const float* __restrict__ gate, float* __restrict__ partO,
    float* __restrict__ partD) {
  __shared__ alignas(16) float blds[16][JC];   // 32 KB bias; reused as accL
  __shared__ alignas(16) char plds[4 * 2048];  // 8 KB P transpose
  __shared__ float dls[4][16];
  const int h = blockIdx.z, it = blockIdx.x, jc = blockIdx.y;
  const int i0 = it * 16;
  const int tid = threadIdx.x, lane = tid & 63, wave = tid >> 6;
  const int g = lane >> 4, li = lane & 15;
  char* myP = plds + wave * 2048;
  // phase A: stage bias tile [16][512] f32, 1KB-contiguous DMA, 8 ops/wave
  const float* bh =
      bias + (size_t)h * L_SEQ * L_SEQ + (size_t)i0 * L_SEQ + jc * JC;
#pragma unroll
  for (int q = 0; q < 4; ++q) {
    const int r = 4 * wave + q;
    const char* gsrc = (const char*)(bh + (size_t)r * L_SEQ) + lane * 16;
    gld_lds16(&blds[r][0], gsrc);
    gld_lds16(&blds[r][256], gsrc + 1024);
  }
  const s16x8* Qv = (const s16x8*)(Qb + (((size_t)h * L_SEQ + i0) << 6));
  const s16x8 qf0 = Qv[li * 8 + g];
  const s16x8 qf1 = Qv[li * 8 + 4 + g];
  const float gh = gate[h];
  const s16x8* Kall = (const s16x8*)(Kb + (((size_t)h * L_SEQ) << 6));
  f32x4 accO[4] = {};
  f32x4 lpart = {0.f, 0.f, 0.f, 0.f};
  __syncthreads();  // bias tile visible (full drain by design)
#pragma unroll
  for (int st = 0; st < 2; ++st) {
    const int c0 = wave * 128 + st * 64;  // col base within JC
    const int jg = jc * JC + c0;          // global col base
    s16x8 k0[4], k1[4];
#pragma unroll
    for (int nt = 0; nt < 4; ++nt) {
      k0[nt] = Kall[(jg + nt * 16 + li) * 8 + g];
      k1[nt] = Kall[(jg + nt * 16 + li) * 8 + 4 + g];
    }
    f32x4 s[4];
#pragma unroll
    for (int nt = 0; nt < 4; ++nt) {
      f32x4 z = {0.f, 0.f, 0.f, 0.f};
      z = __builtin_amdgcn_mfma_f32_16x16x32_bf16(qf0, k0[nt], z, 0, 0, 0);
      z = __builtin_amdgcn_mfma_f32_16x16x32_bf16(qf1, k1[nt], z, 0, 0, 0);
      s[nt] = z;
    }
    // p = exp(s + gh*bias); denom sums the SAME bf16-rounded values as the
    // numerator (rounding cancels in the normalize)
#pragma unroll
    for (int nt = 0; nt < 4; ++nt)
#pragma unroll
      for (int r = 0; r < 4; ++r) {
        const int row = 4 * g + r;
        float p = __expf(fmaf(gh, blds[row][c0 + nt * 16 + li], s[nt][r]));
        unsigned short pb = f2bf(p);
        lpart[r] += bf2f(pb);
        unsigned b = (unsigned)(row * 128 + (nt * 16 + li) * 2) ^
                     (unsigned)((row & 7) << 4);
        *(unsigned short*)(myP + b) = pb;
      }
    asm volatile("s_waitcnt lgkmcnt(0)" ::: "memory");
    const unsigned b0 = ((unsigned)(li * 128 + 16 * g)) ^ (unsigned)((li & 7) << 4);
    const unsigned b1 = ((unsigned)(li * 128 + 64 + 16 * g)) ^ (unsigned)((li & 7) << 4);
    const s16x8 pa0 = *(const s16x8*)(myP + b0);
    const s16x8 pa1 = *(const s16x8*)(myP + b1);
#pragma unroll
    for (int dt = 0; dt < 4; ++dt) {
      const unsigned short* vb = Vt + (size_t)(h * 64 + dt * 16 + li) * L_SEQ + jg;
      const s16x8 v0 = *(const s16x8*)(vb + 8 * g);
      const s16x8 v1 = *(const s16x8*)(vb + 32 + 8 * g);
      accO[dt] = __builtin_amdgcn_mfma_f32_16x16x32_bf16(pa0, v0, accO[dt], 0, 0, 0);
      accO[dt] = __builtin_amdgcn_mfma_f32_16x16x32_bf16(pa1, v1, accO[dt], 0, 0, 0);
    }
  }
  // denom: reduce per-lane partials across the 16 lanes of each row group
  float lrow[4];
#pragma unroll
  for (int r = 0; r < 4; ++r) {
    float tl = lpart[r];
    tl += __shfl_xor(tl, 1);
    tl += __shfl_xor(tl, 2);
    tl += __shfl_xor(tl, 4);
    tl += __shfl_xor(tl, 8);
    lrow[r] = tl;
  }
  __syncthreads();  // bias reads done; reuse blds as accL [4][16][64]
  float* accL = &blds[0][0];
#pragma unroll
  for (int dt = 0; dt < 4; ++dt)
#pragma unroll
    for (int r = 0; r < 4; ++r)
      accL[(wave * 16 + 4 * g + r) * 64 + dt * 16 + li] = accO[dt][r];
  if (li == 0) {
#pragma unroll
    for (int r = 0; r < 4; ++r) dls[wave][4 * g + r] = lrow[r];
  }
  __syncthreads();
  {
    const int row = tid >> 4;         // 0..15
    const int c4 = (tid & 15) * 4;    // col base
    f32x4 sum = {0.f, 0.f, 0.f, 0.f};
    float ds = 0.f;
#pragma unroll
    for (int w = 0; w < 4; ++w) {
      sum += *(const f32x4*)&accL[(w * 16 + row) * 64 + c4];
      ds += dls[w][row];
    }
    const size_t pb = ((size_t)h * 128 + it) * 4 + jc;
    *(f32x4*)&partO[(pb * 16 + row) * 64 + c4] = sum;
    if ((tid & 15) == 0) partD[pb * 16 + row] = ds;
  }
}

// ------------------------------------------- combine j-chunk partials
__global__ __launch_bounds__(256) void attn_comb_k(
    const float* __restrict__ partO, const float* __restrict__ partD,
    unsigned short* __restrict__ AO) {
  const int it = blockIdx.x, h = blockIdx.y;
  const int tid = threadIdx.x, row = tid >> 4, c4 = (tid & 15) * 4;
  const size_t pb = ((size_t)h * 128 + it) * 4;
  f32x4 sum = {0.f, 0.f, 0.f, 0.f};
  float ds = 0.f;
#pragma unroll
  for (int c = 0; c < 4; ++c) {
    sum += *(const f32x4*)&partO[((pb + c) * 16 + row) * 64 + c4];
    ds += partD[(pb + c) * 16 + row];
  }
  const float inv = 1.0f / ds;
  ushort4 o;
  o.x = f2bf(sum[0] * inv);
  o.y = f2bf(sum[1] * inv);
  o.z = f2bf(sum[2] * inv);
  o.w = f2bf(sum[3] * inv);
  *(ushort4*)(AO + (size_t)(it * 16 + row) * DMODEL + h * 64 + c4) = o;
}

// ------------------------------------------------------------- out proj
__global__ __launch_bounds__(256, 2) void gemm_out_k(
    const unsigned short* __restrict__ A, const unsigned short* __restrict__ Bt,
    const float* __restrict__ bout, float* __restrict__ out) {
  __shared__ alignas(16) unsigned short As[128 * 32], Bs[128 * 32];
  f32x4 acc[4][4] = {};
  gemm_bt_core<DMODEL>(A, Bt, As, Bs, blockIdx.x, blockIdx.y, acc);
  const int lane = threadIdx.x & 63, wave = threadIdx.x >> 6;
  const int g = lane >> 4, li = lane & 15;
  const int wm = (wave >> 1) * 64, wn = (wave & 1) * 64;
#pragma unroll
  for (int mt = 0; mt < 4; ++mt)
#pragma unroll
    for (int nt = 0; nt < 4; ++nt)
#pragma unroll
      for (int r = 0; r < 4; ++r) {
        int i = blockIdx.x * 128 + wm + mt * 16 + 4 * g + r;
        int n = blockIdx.y * 128 + wn + nt * 16 + li;
        out[(size_t)i * DMODEL + n] = acc[mt][nt][r] + bout[n];
      }
}

// ---------------------------------------------------------------- launch
extern "C" void kernel_launch(void* const* d_in, const int* in_sizes, int n_in,
                              void* d_out, int out_size, void* d_ws,
                              size_t ws_size, hipStream_t stream) {
  const float* x = (const float*)d_in[0];
  const float* pb = (const float*)d_in[1];
  const float* gate = (const float*)d_in[2];
  const float* wqkv = (const float*)d_in[3];
  const float* bqkv = (const float*)d_in[4];
  const float* wout = (const float*)d_in[5];
  const float* bout = (const float*)d_in[6];

  unsigned short* ws = (unsigned short*)d_ws;
  unsigned short* xb = ws;
  unsigned short* wqkvb = xb + (size_t)L_SEQ * DMODEL;
  unsigned short* woutb = wqkvb + (size_t)NQKV * DMODEL;
  unsigned short* Qb = woutb + (size_t)DMODEL * DMODEL;
  unsigned short* Kb = Qb + (size_t)NHEADS * L_SEQ * HDIM;
  unsigned short* Vt = Kb + (size_t)NHEADS * L_SEQ * HDIM;
  unsigned short* AO = Vt + (size_t)NHEADS * L_SEQ * HDIM;
  float* partO = (float*)(AO + (size_t)L_SEQ * DMODEL);  // 8192*1024 f32
  float* partD = partO + (size_t)8192 * 1024;            // 8192*16 f32

  cvt_kernel<<<1024, 256, 0, stream>>>(x, wqkv, wout, xb, wqkvb, woutb);
  gemm_qkv_k<<<dim3(16, 24), 256, 0, stream>>>(xb, wqkvb, bqkv, Qb, Kb, Vt);
  attn_fused_k<<<dim3(128, 4, 16), 256, 0, stream>>>(Qb, Kb, Vt, pb, gate,
                                                     partO, partD);
  attn_comb_k<<<dim3(128, 16), 256, 0, stream>>>(partO, partD, AO);
  gemm_out_k<<<dim3(16, 8), 256, 0, stream>>>(AO, woutb, bout, (float*)d_out);
}

// Round 9
// 198.222 us; speedup vs baseline: 1.6824x; 1.0633x over previous
//
#include <hip/hip_runtime.h>
#include <cstdint>
#include <cstddef>

#define L_SEQ  2048
#define DMODEL 1024
#define NHEADS 16
#define HDIM   64
#define NQKV   3072

typedef float f32x4 __attribute__((ext_vector_type(4)));
typedef short s16x8 __attribute__((ext_vector_type(8)));

static __device__ __forceinline__ unsigned short f2bf(float f) {
  unsigned u = __float_as_uint(f);
  return (unsigned short)((u + 0x7fffu + ((u >> 16) & 1u)) >> 16);
}

// async global->LDS, 16B per lane; lds base wave-uniform, global per-lane
static __device__ __forceinline__ void gld_lds16(void* lds, const void* g) {
  __builtin_amdgcn_global_load_lds(
      (const __attribute__((address_space(1))) void*)g,
      (__attribute__((address_space(3))) void*)lds, 16, 0, 0);
}

// ---------------------------------------------------------------- convert
__global__ __launch_bounds__(256) void cvt_kernel(
    const float* __restrict__ x, const float* __restrict__ wqkv,
    const float* __restrict__ wout,
    unsigned short* __restrict__ xb, unsigned short* __restrict__ wqkvb,
    unsigned short* __restrict__ woutb) {
  const int NX = L_SEQ * DMODEL / 4;
  const int NW1 = NQKV * DMODEL / 4;
  const int NW2 = DMODEL * DMODEL / 4;
  const int tot = NX + NW1 + NW2;
  for (int i = blockIdx.x * blockDim.x + threadIdx.x; i < tot;
       i += gridDim.x * blockDim.x) {
    const float4* s;
    unsigned short* d;
    int j;
    if (i < NX) { s = (const float4*)x; d = xb; j = i; }
    else if (i < NX + NW1) { s = (const float4*)wqkv; d = wqkvb; j = i - NX; }
    else { s = (const float4*)wout; d = woutb; j = i - NX - NW1; }
    float4 v = s[j];
    ushort4 o;
    o.x = f2bf(v.x); o.y = f2bf(v.y); o.z = f2bf(v.z); o.w = f2bf(v.w);
    *(ushort4*)(d + 4 * (size_t)j) = o;
  }
}

// ------------------------------------------------- shared 128x128 GEMM core
template <int KDIM>
static __device__ __forceinline__ void gemm_bt_core(
    const unsigned short* __restrict__ A, const unsigned short* __restrict__ Bt,
    unsigned short* As, unsigned short* Bs, int bm, int bn, f32x4 acc[4][4]) {
  const int tid = threadIdx.x;
  const int lane = tid & 63;
  const int wave = tid >> 6;
  const int g = lane >> 4;
  const int li = lane & 15;
  const int wm = (wave >> 1) * 64;
  const int wn = (wave & 1) * 64;
  const int arow = tid >> 2;
  const int acolb = (tid & 3) << 4;
  const char* gA = (const char*)A + (size_t)(bm * 128 + arow) * (KDIM * 2) + acolb;
  const char* gB = (const char*)Bt + (size_t)(bn * 128 + arow) * (KDIM * 2) + acolb;
  char* lA = (char*)As + wave * 1024;
  char* lB = (char*)Bs + wave * 1024;
  const size_t half = (size_t)64 * KDIM * 2;
  for (int kt = 0; kt < KDIM; kt += 32) {
    __syncthreads();
    gld_lds16(lA, gA + kt * 2);
    gld_lds16(lA + 4096, gA + half + kt * 2);
    gld_lds16(lB, gB + kt * 2);
    gld_lds16(lB + 4096, gB + half + kt * 2);
    __syncthreads();
    const s16x8* Av = (const s16x8*)As;
    const s16x8* Bv = (const s16x8*)Bs;
    s16x8 af[4], bfv[4];
#pragma unroll
    for (int mt = 0; mt < 4; ++mt) af[mt] = Av[(wm + mt * 16 + li) * 4 + g];
#pragma unroll
    for (int nt = 0; nt < 4; ++nt) bfv[nt] = Bv[(wn + nt * 16 + li) * 4 + g];
#pragma unroll
    for (int mt = 0; mt < 4; ++mt)
#pragma unroll
      for (int nt = 0; nt < 4; ++nt)
        acc[mt][nt] = __builtin_amdgcn_mfma_f32_16x16x32_bf16(
            af[mt], bfv[nt], acc[mt][nt], 0, 0, 0);
  }
}

// ------------------------------------------------------------- QKV GEMM
__global__ __launch_bounds__(256, 2) void gemm_qkv_k(
    const unsigned short* __restrict__ A, const unsigned short* __restrict__ Bt,
    const float* __restrict__ bqkv, unsigned short* __restrict__ Qb,
    unsigned short* __restrict__ Kb, unsigned short* __restrict__ Vt) {
  __shared__ alignas(16) unsigned short As[128 * 32], Bs[128 * 32];
  f32x4 acc[4][4] = {};
  gemm_bt_core<DMODEL>(A, Bt, As, Bs, blockIdx.x, blockIdx.y, acc);
  const int lane = threadIdx.x & 63, wave = threadIdx.x >> 6;
  const int g = lane >> 4, li = lane & 15;
  const int wm = (wave >> 1) * 64, wn = (wave & 1) * 64;
#pragma unroll
  for (int mt = 0; mt < 4; ++mt)
#pragma unroll
    for (int nt = 0; nt < 4; ++nt)
#pragma unroll
      for (int r = 0; r < 4; ++r) {
        int i = blockIdx.x * 128 + wm + mt * 16 + 4 * g + r;
        int n = blockIdx.y * 128 + wn + nt * 16 + li;
        float v = acc[mt][nt][r] + bqkv[n];
        int s = n >> 10;
        int h = (n >> 6) & 15;
        int d = n & 63;
        if (s == 0)      Qb[(((size_t)h * L_SEQ + i) << 6) + d] = f2bf(v * 0.125f);
        else if (s == 1) Kb[(((size_t)h * L_SEQ + i) << 6) + d] = f2bf(v);
        else             Vt[(size_t)(h * 64 + d) * L_SEQ + i] = f2bf(v);
      }
}

// ------------------------------------------------------------- attention
// grid (128 i-tiles, 16 heads); 4 waves split the 256-col j-chunk; 8 iters.
// Bias: 1KB-contiguous f32x4 register loads, prefetch depth 2 (rbA=t+1,
// rbB=t+2), staged to a double-buffered swizzled LDS tile at iter end.
// VMEM issue order K -> V -> bias pinned by sched_barrier(0): every implicit
// K/V-use vmcnt leaves the 16 youngest (bias) ops in flight; one raw
// s_barrier + lgkmcnt(0) per iter; no vmcnt drains anywhere in the loop.
__global__ __launch_bounds__(256, 2) void attn_k(
    const unsigned short* __restrict__ Qb, const unsigned short* __restrict__ Kb,
    const unsigned short* __restrict__ Vt, const float* __restrict__ bias,
    const float* __restrict__ gate, unsigned short* __restrict__ AO) {
  __shared__ alignas(16) float blds[2][16][256];  // 32 KB bias double-buffer
  __shared__ alignas(16) char plds[4 * 2048];     // 8 KB P transpose
  __shared__ float dls[4][16];
  const int h = blockIdx.y;
  const int i0 = blockIdx.x * 16;
  const int tid = threadIdx.x, lane = tid & 63, wave = tid >> 6;
  const int g = lane >> 4, li = lane & 15;
  char* myP = plds + wave * 2048;
  const s16x8* Qv = (const s16x8*)(Qb + (((size_t)h * L_SEQ + i0) << 6));
  const s16x8 qf0 = Qv[li * 8 + g];
  const s16x8 qf1 = Qv[li * 8 + 4 + g];
  const float gh = gate[h];
  const float* bh = bias + (size_t)h * L_SEQ * L_SEQ + (size_t)i0 * L_SEQ;
  const s16x8* Kall = (const s16x8*)(Kb + (((size_t)h * L_SEQ) << 6));
  const int srow = wave * 4;  // this wave stages bias rows srow..srow+3
  f32x4 accO[4] = {};
  f32x4 lpart = {0.f, 0.f, 0.f, 0.f};

  f32x4 rbA[4], rbB[4];
  // prologue: bias(0) -> rbA, bias(1) -> rbB (rbB stays in flight)
#pragma unroll
  for (int q = 0; q < 4; ++q)
    rbA[q] = *(const f32x4*)(bh + (size_t)(srow + q) * L_SEQ + 4 * lane);
#pragma unroll
  for (int q = 0; q < 4; ++q)
    rbB[q] = *(const f32x4*)(bh + (size_t)(srow + q) * L_SEQ + 256 + 4 * lane);
  __builtin_amdgcn_sched_barrier(0);
  // write bias(0) -> buf0 (swizzled); compiler waits only rbA (rbB younger)
#pragma unroll
  for (int q = 0; q < 4; ++q) {
    const int rr = srow + q;
    char* dst = (char*)&blds[0][rr][0] + ((unsigned)(lane * 16) ^ ((rr & 7) << 4));
    *(f32x4*)dst = rbA[q];
  }
#pragma unroll
  for (int q = 0; q < 4; ++q) rbA[q] = rbB[q];  // rbA = bias(1)
  asm volatile("s_waitcnt lgkmcnt(0)" ::: "memory");
  __builtin_amdgcn_s_barrier();

  for (int t = 0; t < 8; ++t) {
    const int jg = t * 256 + wave * 64;
    // --- issue K (8 ops), V (8 ops): L2-resident
    s16x8 k0[4], k1[4];
#pragma unroll
    for (int nt = 0; nt < 4; ++nt) {
      k0[nt] = Kall[(jg + nt * 16 + li) * 8 + g];
      k1[nt] = Kall[(jg + nt * 16 + li) * 8 + 4 + g];
    }
    s16x8 v0[4], v1[4];
#pragma unroll
    for (int dt = 0; dt < 4; ++dt) {
      const unsigned short* vb = Vt + (size_t)(h * 64 + dt * 16 + li) * L_SEQ + jg;
      v0[dt] = *(const s16x8*)(vb + 8 * g);
      v1[dt] = *(const s16x8*)(vb + 32 + 8 * g);
    }
    __builtin_amdgcn_sched_barrier(0);
    // --- issue bias(t+2) last (youngest -> survives all implicit waits)
    if (t < 6) {
#pragma unroll
      for (int q = 0; q < 4; ++q)
        rbB[q] = *(const f32x4*)(bh + (size_t)(srow + q) * L_SEQ +
                                 (t + 2) * 256 + 4 * lane);
    }
    __builtin_amdgcn_sched_barrier(0);
    // --- QK^T (implicit wait for K leaves V+bias in flight)
    f32x4 s[4];
#pragma unroll
    for (int nt = 0; nt < 4; ++nt) {
      f32x4 z = {0.f, 0.f, 0.f, 0.f};
      z = __builtin_amdgcn_mfma_f32_16x16x32_bf16(qf0, k0[nt], z, 0, 0, 0);
      z = __builtin_amdgcn_mfma_f32_16x16x32_bf16(qf1, k1[nt], z, 0, 0, 0);
      s[nt] = z;
    }
    // --- exp from LDS buf[t&1] (swizzled read); P -> wave-private LDS
    const float* blr = &blds[t & 1][0][0];
#pragma unroll
    for (int nt = 0; nt < 4; ++nt)
#pragma unroll
      for (int r = 0; r < 4; ++r) {
        const int row = 4 * g + r;
        const char* src = (const char*)(blr + row * 256) +
                          ((unsigned)((wave * 64 + nt * 16 + li) * 4) ^
                           ((row & 7) << 4));
        float p = __expf(fmaf(gh, *(const float*)src, s[nt][r]));
        lpart[r] += p;
        unsigned b = (unsigned)(row * 128 + (nt * 16 + li) * 2) ^
                     (unsigned)((row & 7) << 4);
        *(unsigned short*)(myP + b) = f2bf(p);
      }
    asm volatile("s_waitcnt lgkmcnt(0)" ::: "memory");
    const unsigned b0 = ((unsigned)(li * 128 + 16 * g)) ^ (unsigned)((li & 7) << 4);
    const unsigned b1 = ((unsigned)(li * 128 + 64 + 16 * g)) ^ (unsigned)((li & 7) << 4);
    const s16x8 pa0 = *(const s16x8*)(myP + b0);
    const s16x8 pa1 = *(const s16x8*)(myP + b1);
    // --- PV (implicit wait for V leaves bias in flight)
#pragma unroll
    for (int dt = 0; dt < 4; ++dt) {
      accO[dt] = __builtin_amdgcn_mfma_f32_16x16x32_bf16(pa0, v0[dt], accO[dt], 0, 0, 0);
      accO[dt] = __builtin_amdgcn_mfma_f32_16x16x32_bf16(pa1, v1[dt], accO[dt], 0, 0, 0);
    }
    // --- stage bias(t+1) regs -> buf[(t+1)&1]; rotate rbA <- rbB
    if (t < 7) {
#pragma unroll
      for (int q = 0; q < 4; ++q) {
        const int rr = srow + q;
        char* dst = (char*)&blds[(t + 1) & 1][rr][0] +
                    ((unsigned)(lane * 16) ^ ((rr & 7) << 4));
        *(f32x4*)dst = rbA[q];
      }
#pragma unroll
      for (int q = 0; q < 4; ++q) rbA[q] = rbB[q];
    }
    asm volatile("s_waitcnt lgkmcnt(0)" ::: "memory");
    __builtin_amdgcn_s_barrier();  // raw: no vmcnt drain
  }
  // denom across the 16 lanes of each row group
  float lrow[4];
#pragma unroll
  for (int r = 0; r < 4; ++r) {
    float tl = lpart[r];
    tl += __shfl_xor(tl, 1);
    tl += __shfl_xor(tl, 2);
    tl += __shfl_xor(tl, 4);
    tl += __shfl_xor(tl, 8);
    lrow[r] = tl;
  }
  __syncthreads();
  float* accL = &blds[0][0][0];  // reuse: [4][16][64] f32 = 16KB
#pragma unroll
  for (int dt = 0; dt < 4; ++dt)
#pragma unroll
    for (int r = 0; r < 4; ++r)
      accL[(wave * 16 + 4 * g + r) * 64 + dt * 16 + li] = accO[dt][r];
  if (li == 0) {
#pragma unroll
    for (int r = 0; r < 4; ++r) dls[wave][4 * g + r] = lrow[r];
  }
  __syncthreads();
  {
    const int row = tid >> 4;
    const int c4 = (tid & 15) * 4;
    f32x4 sum = {0.f, 0.f, 0.f, 0.f};
    float ds = 0.f;
#pragma unroll
    for (int w = 0; w < 4; ++w) {
      sum += *(const f32x4*)&accL[(w * 16 + row) * 64 + c4];
      ds += dls[w][row];
    }
    const float inv = 1.0f / ds;
    ushort4 o;
    o.x = f2bf(sum[0] * inv);
    o.y = f2bf(sum[1] * inv);
    o.z = f2bf(sum[2] * inv);
    o.w = f2bf(sum[3] * inv);
    *(ushort4*)(AO + (size_t)(i0 + row) * DMODEL + h * 64 + c4) = o;
  }
}

// ------------------------------------------------------------- out proj
__global__ __launch_bounds__(256, 2) void gemm_out_k(
    const unsigned short* __restrict__ A, const unsigned short* __restrict__ Bt,
    const float* __restrict__ bout, float* __restrict__ out) {
  __shared__ alignas(16) unsigned short As[128 * 32], Bs[128 * 32];
  f32x4 acc[4][4] = {};
  gemm_bt_core<DMODEL>(A, Bt, As, Bs, blockIdx.x, blockIdx.y, acc);
  const int lane = threadIdx.x & 63, wave = threadIdx.x >> 6;
  const int g = lane >> 4, li = lane & 15;
  const int wm = (wave >> 1) * 64, wn = (wave & 1) * 64;
#pragma unroll
  for (int mt = 0; mt < 4; ++mt)
#pragma unroll
    for (int nt = 0; nt < 4; ++nt)
#pragma unroll
      for (int r = 0; r < 4; ++r) {
        int i = blockIdx.x * 128 + wm + mt * 16 + 4 * g + r;
        int n = blockIdx.y * 128 + wn + nt * 16 + li;
        out[(size_t)i * DMODEL + n] = acc[mt][nt][r] + bout[n];
      }
}

// ---------------------------------------------------------------- launch
extern "C" void kernel_launch(void* const* d_in, const int* in_sizes, int n_in,
                              void* d_out, int out_size, void* d_ws,
                              size_t ws_size, hipStream_t stream) {
  const float* x = (const float*)d_in[0];
  const float* pb = (const float*)d_in[1];
  const float* gate = (const float*)d_in[2];
  const float* wqkv = (const float*)d_in[3];
  const float* bqkv = (const float*)d_in[4];
  const float* wout = (const float*)d_in[5];
  const float* bout = (const float*)d_in[6];

  unsigned short* ws = (unsigned short*)d_ws;
  unsigned short* xb = ws;
  unsigned short* wqkvb = xb + (size_t)L_SEQ * DMODEL;
  unsigned short* woutb = wqkvb + (size_t)NQKV * DMODEL;
  unsigned short* Qb = woutb + (size_t)DMODEL * DMODEL;
  unsigned short* Kb = Qb + (size_t)NHEADS * L_SEQ * HDIM;
  unsigned short* Vt = Kb + (size_t)NHEADS * L_SEQ * HDIM;
  unsigned short* AO = Vt + (size_t)NHEADS * L_SEQ * HDIM;

  cvt_kernel<<<1024, 256, 0, stream>>>(x, wqkv, wout, xb, wqkvb, woutb);
  gemm_qkv_k<<<dim3(16, 24), 256, 0, stream>>>(xb, wqkvb, bqkv, Qb, Kb, Vt);
  attn_k<<<dim3(128, 16), 256, 0, stream>>>(Qb, Kb, Vt, pb, gate, AO);
  gemm_out_k<<<dim3(16, 8), 256, 0, stream>>>(AO, woutb, bout, (float*)d_out);
}